// Round 19
// baseline (161.585 us; speedup 1.0000x reference)
//
#include <hip/hip_runtime.h>
#include <math.h>

#define H_DIM 256
#define HEADS 4
#define HD 64
#define TOPK 15
#define NSLOPE 0.2
#define NSLOPEF 0.2f
#define EDGE_CAP_MAX 128
#define CAND_CAP 256
#define SROWS 16  // rows per s-compute block in prep2

// prep1: 16 blocks. All zero cnt (4096 ints); blocks 0..7 compute wa for
// (head = b>>1, side = b&1); block 8 packs active[] into 4096-bit abits.
__global__ __launch_bounds__(256) void prep1_kernel(const float* __restrict__ W,
                                                    const float* __restrict__ att,
                                                    double* __restrict__ wa_dst,
                                                    double* __restrict__ wa_src,
                                                    int* __restrict__ cnt,
                                                    unsigned int* __restrict__ abits,
                                                    const int* __restrict__ active) {
    const int b = blockIdx.x;
    cnt[b * 256 + threadIdx.x] = 0;
    if (b < 2 * HEADS) {
        const int k = threadIdx.x;
        const int h = b >> 1;
        const int side = b & 1;
        double a = 0.0;
        for (int d = 0; d < HD; ++d)
            a += (double)W[(h * HD + d) * H_DIM + k] * (double)att[h * 2 * HD + side * HD + d];
        (side ? wa_src : wa_dst)[h * H_DIM + k] = a;
    } else if (b == 8 && threadIdx.x < 128) {
        const int* ap = active + threadIdx.x * 32;
        unsigned int wv = 0;
        for (int t = 0; t < 32; ++t)
            if (ap[t]) wv |= 1u << t;
        abits[threadIdx.x] = wv;
    }
}

// prep2, partitioned by blockIdx:
//   [0, N)              mask pack: block per row; coalesced int4 mask read +
//                       intra-wave bit-transpose -> packed[i*256+tid] holds
//                       the wave-local ownership mask pm (active folded in).
//   [N, N+sblocks)      s-compute: 16 rows/block, wa+emb staged in LDS once
//   [N+sblocks, +nb)    edge-table build: one int4 {col,eid,w_bits,0} per edge
__global__ __launch_bounds__(256) void prep2_kernel(
    const float* __restrict__ emb, const double* __restrict__ wa_dst,
    const double* __restrict__ wa_src, double* __restrict__ s_dst,
    double* __restrict__ s_src, float* __restrict__ s_dst_f,
    float* __restrict__ s_src_f, const int* __restrict__ eidx,
    const float* __restrict__ ew, int* __restrict__ cnt,
    int4* __restrict__ etab, const int* __restrict__ sector_mask,
    const unsigned short* __restrict__ abits16, const int* __restrict__ active,
    unsigned short* __restrict__ packed, int N, int E, int cap, int sblocks) {
    const int b = blockIdx.x;
    const int tid = threadIdx.x;

    if (b < N) {
        // ---- mask pack (exact copy of main's phase-0 logic) ----
        const int i = b;
        const int lane = tid & 63;
        const int* mrow = sector_mask + (size_t)i * N;
        const int4 m0 = *(const int4*)(mrow + 16 * tid);
        const int4 m1 = *(const int4*)(mrow + 16 * tid + 4);
        const int4 m2 = *(const int4*)(mrow + 16 * tid + 8);
        const int4 m3 = *(const int4*)(mrow + 16 * tid + 12);
        unsigned int pb = 0;
#define PB(C, VAL) if ((VAL) != 0) pb |= (1u << (C));
        PB(0, m0.x)  PB(1, m0.y)  PB(2, m0.z)  PB(3, m0.w)
        PB(4, m1.x)  PB(5, m1.y)  PB(6, m1.z)  PB(7, m1.w)
        PB(8, m2.x)  PB(9, m2.y)  PB(10, m2.z) PB(11, m2.w)
        PB(12, m3.x) PB(13, m3.y) PB(14, m3.z) PB(15, m3.w)
#undef PB
        pb &= (unsigned int)abits16[tid];
        // Intra-wave bit-transpose: col j=(wid<<10)|(k<<6)|lane was loaded by
        // lane 4k+(lane>>4) of the SAME wave, bit (lane&15) of its pb.
        const int lhi = lane >> 4;
        const int llo = lane & 15;
        unsigned int pm = 0;
#pragma unroll
        for (int k = 0; k < 16; ++k) {
            const unsigned int opb = (unsigned int)__shfl((int)pb, 4 * k + lhi, 64);
            pm |= ((opb >> llo) & 1u) << k;
        }
        if (active[i] == 0) pm = 0;
        packed[i * 256 + tid] = (unsigned short)pm;
    } else if (b < N + sblocks) {
        // ---- s-compute ----
        __shared__ double wa_l[8][258];   // +2 pad: conflict-free
        __shared__ float emb_l[SROWS][258];
        const int i0 = (b - N) * SROWS;
#pragma unroll
        for (int c = 0; c < 8; ++c)
            wa_l[c][tid] = ((c & 1) ? wa_src : wa_dst)[(c >> 1) * H_DIM + tid];
#pragma unroll
        for (int r = 0; r < SROWS; ++r)
            emb_l[r][tid] = emb[(size_t)(i0 + r) * H_DIM + tid];
        __syncthreads();

        const int j = tid >> 1;        // job 0..127: row r=j>>3, combo c=j&7
        const int half = tid & 1;      // low/high 128-element half
        const int r = j >> 3;
        const int c = j & 7;
        const int base = half * 128;
        double acc = 0.0;
#pragma unroll 8
        for (int k = 0; k < 128; ++k)
            acc += (double)emb_l[r][base + k] * wa_l[c][base + k];
        const double other = __shfl_xor(acc, 1, 64);
        const double lo = half ? other : acc;
        const double hi = half ? acc : other;
        const double s = lo + hi;      // fixed order: low half + high half
        if (half == 0) {
            const int i = i0 + r;
            const int h = c >> 1;
            if (c & 1) {
                s_src[i * HEADS + h] = s;
                s_src_f[i * HEADS + h] = (float)s;
            } else {
                s_dst[i * HEADS + h] = s;
                s_dst_f[i * HEADS + h] = (float)s;
            }
        }
    } else {
        // ---- edge-table build (slot order nondeterministic; dedup is by max
        // edge id, which is order-independent) ----
        const int e = (b - N - sblocks) * 256 + tid;
        if (e < E) {
            const int r = eidx[e];
            const int cc = eidx[E + e];
            const int s = atomicAdd(&cnt[r], 1);
            if (s < cap) {
                int4 rec;
                rec.x = cc;
                rec.y = e;
                rec.z = __float_as_int(ew[e]);
                rec.w = 0;
                etab[r * cap + s] = rec;
            }
        }
    }
}

#define FOR16(OP) OP(0) OP(1) OP(2) OP(3) OP(4) OP(5) OP(6) OP(7) \
                  OP(8) OP(9) OP(10) OP(11) OP(12) OP(13) OP(14) OP(15)

// One block per row. Wave-local ownership: thread (wave w, lane l) owns
// columns j = (w<<10)|(k<<6)|l; ownership mask pre-packed by prep2 (one
// ushort load, L2-resident). Winner adds via 8 KB ushort index table +
// fp32/fp64 add arrays (branchless gather; tab16 answers phase 4a directly).
// fp32 selection (truncated+relaxed ballot threshold -> provable superset);
// exact fp64 re-rank by (value, index) -> output identical to all-fp64.
__global__ __launch_bounds__(256, 8) void main_kernel(
    const double* __restrict__ s_dst, const double* __restrict__ s_src,
    const float* __restrict__ s_dst_f, const float* __restrict__ s_src_f,
    const unsigned short* __restrict__ packed, const float* __restrict__ lam_p,
    const int* __restrict__ cnt, const int4* __restrict__ etab,
    float* __restrict__ out, int N, int cap) {
    const int i = blockIdx.x;
    const int tid = threadIdx.x;
    const int lane = tid & 63;
    const int wid = tid >> 6;

    __shared__ int ec[EDGE_CAP_MAX];
    __shared__ int ee[EDGE_CAP_MAX];
    __shared__ float ewl[EDGE_CAP_MAX];
    __shared__ double wadd[EDGE_CAP_MAX];      // fp64 winner add by slot
    __shared__ unsigned short tab16[4096];     // winner slot+1 per column (8 KB)
    __shared__ float waddf[EDGE_CAP_MAX + 2];  // fp32 adds; [0] = 0.0 sentinel
    __shared__ unsigned int wth[4];
    __shared__ double cand_v[CAND_CAP];
    __shared__ int cand_i[CAND_CAP];
    __shared__ int cand_cnt, wcnt;
    __shared__ double sorted_v[TOPK];
    __shared__ int sorted_i[TOPK];
    __shared__ double exps[TOPK];

    // Ownership mask: one ushort load (packed by prep2, active folded in).
    const unsigned int pm = (unsigned int)packed[i * 256 + tid];

    if (tid == 0) { cand_cnt = 0; wcnt = 0; waddf[0] = 0.0f; }

    // Zero tab16 as 2048 ints at dword stride-256: conflict-free.
    {
        int* t4 = (int*)tab16;
#pragma unroll
        for (int z = 0; z < 8; ++z) t4[tid + (z << 8)] = 0;
    }

    // Stage this row's edge slice (one int4 per edge, unpacked to scalar LDS
    // arrays).
    int deg = cnt[i];
    if (deg > cap) deg = cap;
    for (int p = tid; p < deg; p += 256) {
        const int4 rec = etab[i * cap + p];
        ec[p] = rec.x;
        ee[p] = rec.y;
        ewl[p] = __int_as_float(rec.z);
    }
    __syncthreads();  // edges + zeroed table + counters visible

    // fp32 sd for selection; fp64 sd for exact re-rank
    const float sdf0 = s_dst_f[i * 4 + 0];
    const float sdf1 = s_dst_f[i * 4 + 1];
    const float sdf2 = s_dst_f[i * 4 + 2];
    const float sdf3 = s_dst_f[i * 4 + 3];
    const double sd0 = s_dst[i * 4 + 0];
    const double sd1 = s_dst[i * 4 + 1];
    const double sd2 = s_dst[i * 4 + 2];
    const double sd3 = s_dst[i * 4 + 3];
    const double lam = (double)lam_p[0];
    const double4* __restrict__ s_src4 = (const double4*)s_src;
    const float4* __restrict__ s_srcf4 = (const float4*)s_src_f;
    const int jbase = (wid << 10) | lane;  // owned column for k: jbase + (k<<6)

    // Phase 1 (fp32): scores into 16 named registers (coalesced per-wave)
    float f0, f1, f2, f3, f4, f5, f6, f7, f8, f9, f10, f11, f12, f13, f14, f15;
#define INIT_SLOT(K) { \
    const bool m = (pm >> K) & 1u; \
    const float4 sv = s_srcf4[jbase + (K << 6)]; \
    float x0 = sdf0 + sv.x, x1 = sdf1 + sv.y, x2 = sdf2 + sv.z, x3 = sdf3 + sv.w; \
    x0 = (x0 < 0.0f) ? NSLOPEF * x0 : x0; \
    x1 = (x1 < 0.0f) ? NSLOPEF * x1 : x1; \
    x2 = (x2 < 0.0f) ? NSLOPEF * x2 : x2; \
    x3 = (x3 < 0.0f) ? NSLOPEF * x3 : x3; \
    f##K = m ? (0.25f * (x0 + x1 + x2 + x3)) : -INFINITY; }
    FOR16(INIT_SLOT)
#undef INIT_SLOT

    // Phase 2a: parallel dedup (last-write-wins by edge id), thread-per-edge.
    // Winners: slot index into tab16 (unique columns -> conflict-free) +
    // fp64/fp32 adds by slot.
    if (tid < deg) {
        const int c = ec[tid];
        const int eid = ee[tid];
        bool win = true;
        for (int q = 0; q < deg; ++q)
            if (ec[q] == c && ee[q] > eid) win = false;
        if (win) {
            const double a = lam * (double)ewl[tid];
            int p = atomicAdd(&wcnt, 1);
            wadd[p] = a;
            waddf[p + 1] = (float)a;
            tab16[c] = (unsigned short)(p + 1);
        }
    }
    __syncthreads();

    // Phase 2b (fp32): branchless gather (x+0.0f == x; -0.0f+0.0f -> +0.0f
    // shifts a key 1 step — absorbed by the relax; fp64 re-rank recomputes).
#define ADDG(K) f##K += waddf[tab16[jbase + (K << 6)]];
    FOR16(ADDG)
#undef ADDG

    // Phase 3a: fp32 monotone keys + per-thread local max
    unsigned int k0, k1, k2, k3, k4, k5, k6, k7, k8, k9, k10, k11, k12, k13, k14, k15;
#define KEY_SLOT(K) { const unsigned u = __float_as_uint(f##K); \
    k##K = u ^ ((unsigned)((int)u >> 31) | 0x80000000u); }
    FOR16(KEY_SLOT)
#undef KEY_SLOT
    unsigned int lmax = k0;
#define LMAX(K) if (k##K > lmax) lmax = k##K;
    FOR16(LMAX)
#undef LMAX

    // Phase 3b: per-wave 15th-largest lane-max via ballot binary search,
    // truncated to the top 24 bits (threshold only gets lower -> still a
    // valid lower bound on the row's true 15th value).
    unsigned int th = 0;
    for (int b = 31; b >= 8; --b) {
        const unsigned int trial = th | (1u << b);
        unsigned long long m = __ballot(lmax >= trial);
        if (__popcll(m) >= TOPK) th = trial;
    }
    if (lane == 0) wth[wid] = th;
    __syncthreads();
    th = wth[0];
    if (wth[1] > th) th = wth[1];
    if (wth[2] > th) th = wth[2];
    if (wth[3] > th) th = wth[3];
    // Relax by 256 ulp: covers fp32-vs-fp64 ordering divergence near the cut.
    th = (th > 256u) ? (th - 256u) : 0u;

    // Phase 3c: candidate filter (store actual column index)
#define FILT(K) if (k##K >= th) { int p = atomicAdd(&cand_cnt, 1); \
    if (p < CAND_CAP) cand_i[p] = jbase + (K << 6); }
    FOR16(FILT)
#undef FILT
    __syncthreads();

    // Phase 4a: exact fp64 re-score of each candidate (same expression order
    // as the all-fp64 kernel; winner lookup via tab16 — at most one/column)
    int C = cand_cnt;
    if (C > CAND_CAP) C = CAND_CAP;
    if (tid < C) {
        const int j = cand_i[tid];
        const double4 sv = s_src4[j];
        double x0 = sd0 + sv.x, x1 = sd1 + sv.y, x2 = sd2 + sv.z, x3 = sd3 + sv.w;
        x0 = (x0 < 0.0) ? NSLOPE * x0 : x0;
        x1 = (x1 < 0.0) ? NSLOPE * x1 : x1;
        x2 = (x2 < 0.0) ? NSLOPE * x2 : x2;
        x3 = (x3 < 0.0) ? NSLOPE * x3 : x3;
        double v = 0.25 * (x0 + x1 + x2 + x3);
        const int slot = tab16[j];
        if (slot) v += wadd[slot - 1];
        cand_v[tid] = v;
    }
    __syncthreads();

    // Phase 4b: exact fp64 rank-by-counting among C candidates (unique ranks)
    if (tid < C) {
        const double mv = cand_v[tid];
        const int mi = cand_i[tid];
        int rank = 0;
        for (int q = 0; q < C; ++q) {
            const double qv = cand_v[q];
            const int qi = cand_i[q];
            rank += ((qv > mv) || (qv == mv && qi < mi)) ? 1 : 0;
        }
        if (rank < TOPK) { sorted_v[rank] = mv; sorted_i[rank] = mi; }
    }
    __syncthreads();

    // Phase 5: softmax + store (fp64)
    if (tid < TOPK) exps[tid] = exp(sorted_v[tid] - sorted_v[0]);
    __syncthreads();
    if (tid < TOPK) {
        double s = 0.0;
        for (int t = 0; t < TOPK; ++t) s += exps[t];
        const int NK = N * TOPK;
        const int base = i * TOPK + tid;
        out[base] = (float)sorted_i[tid];      // edge_index row 0: topk column idx
        out[NK + base] = (float)i;             // edge_index row 1: source row
        out[2 * NK + base] = (float)(exps[tid] / s);  // edge_weight (softmax)
    }
}

extern "C" void kernel_launch(void* const* d_in, const int* in_sizes, int n_in,
                              void* d_out, int out_size, void* d_ws, size_t ws_size,
                              hipStream_t stream) {
    const float* emb    = (const float*)d_in[0];
    const float* W      = (const float*)d_in[1];
    const float* att    = (const float*)d_in[2];
    const float* lam    = (const float*)d_in[3];
    const int*   sector = (const int*)d_in[4];
    const int*   active = (const int*)d_in[5];
    const int*   eidx   = (const int*)d_in[6];
    const float* ew     = (const float*)d_in[7];
    float* out = (float*)d_out;

    const int N = in_sizes[5];      // 4096
    const int E = in_sizes[6] / 2;  // 131072

    // workspace layout
    double* wa_dst = (double*)d_ws;                       // 1024 dbl
    double* wa_src = wa_dst + HEADS * H_DIM;              // 1024 dbl
    double* s_dst  = wa_src + HEADS * H_DIM;              // N*4 dbl
    double* s_src  = s_dst + (size_t)N * HEADS;           // N*4 dbl
    float* s_dst_f = (float*)(s_src + (size_t)N * HEADS); // N*4 f32
    float* s_src_f = s_dst_f + (size_t)N * HEADS;         // N*4 f32
    int* cnt       = (int*)(s_src_f + (size_t)N * HEADS); // N int
    unsigned int* abits = (unsigned int*)(cnt + N);       // N/32 uint
    unsigned short* packed = (unsigned short*)(abits + N / 32);  // N*256 ushort (2 MB)
    // 16B-align the edge table
    uintptr_t ep = (uintptr_t)(packed + (size_t)N * 256);
    ep = (ep + 15) & ~(uintptr_t)15;
    int4* etab = (int4*)ep;

    size_t used = (ep - (uintptr_t)d_ws) + 64;
    size_t rem = (ws_size > used) ? (ws_size - used) : 0;
    int cap = (int)(rem / ((size_t)N * 16));
    if (cap > EDGE_CAP_MAX) cap = EDGE_CAP_MAX;
    if (cap < 16) cap = 16;

    const int nb = (E + 255) / 256;   // edge-build blocks (512)
    const int sblocks = N / SROWS;    // s-compute blocks (256)

    prep1_kernel<<<16, 256, 0, stream>>>(W, att, wa_dst, wa_src, cnt, abits, active);
    prep2_kernel<<<N + sblocks + nb, 256, 0, stream>>>(emb, wa_dst, wa_src, s_dst,
                                                       s_src, s_dst_f, s_src_f, eidx,
                                                       ew, cnt, etab, sector,
                                                       (const unsigned short*)abits,
                                                       active, packed, N, E, cap,
                                                       sblocks);
    main_kernel<<<N, 256, 0, stream>>>(s_dst, s_src, s_dst_f, s_src_f, packed, lam,
                                       cnt, etab, out, N, cap);
}

// Round 20
// 156.179 us; speedup vs baseline: 1.0346x; 1.0346x over previous
//
#include <hip/hip_runtime.h>
#include <math.h>

#define H_DIM 256
#define HEADS 4
#define HD 64
#define TOPK 15
#define NSLOPE 0.2
#define NSLOPEF 0.2f
#define EDGE_CAP_MAX 128
#define CAND_CAP 256
#define SROWS 16  // rows per s-compute block in prep2

// prep1: 16 blocks. All zero cnt (4096 ints); blocks 0..7 compute wa for
// (head = b>>1, side = b&1); block 8 packs active[] into 4096-bit abits.
__global__ __launch_bounds__(256) void prep1_kernel(const float* __restrict__ W,
                                                    const float* __restrict__ att,
                                                    double* __restrict__ wa_dst,
                                                    double* __restrict__ wa_src,
                                                    int* __restrict__ cnt,
                                                    unsigned int* __restrict__ abits,
                                                    const int* __restrict__ active) {
    const int b = blockIdx.x;
    cnt[b * 256 + threadIdx.x] = 0;
    if (b < 2 * HEADS) {
        const int k = threadIdx.x;
        const int h = b >> 1;
        const int side = b & 1;
        double a = 0.0;
        for (int d = 0; d < HD; ++d)
            a += (double)W[(h * HD + d) * H_DIM + k] * (double)att[h * 2 * HD + side * HD + d];
        (side ? wa_src : wa_dst)[h * H_DIM + k] = a;
    } else if (b == 8 && threadIdx.x < 128) {
        const int* ap = active + threadIdx.x * 32;
        unsigned int wv = 0;
        for (int t = 0; t < 32; ++t)
            if (ap[t]) wv |= 1u << t;
        abits[threadIdx.x] = wv;
    }
}

// prep2, partitioned by blockIdx:
//   [0, N/16)           s-compute: 16 rows/block, wa+emb staged in LDS once,
//                       2 threads per (row,combo) dot product (serial 128-FMA
//                       halves + one shuffle combine, fixed low+high order)
//   [N/16, N/16+nb)     edge-table build: one int4 {col,eid,w_bits,0} per edge
__global__ __launch_bounds__(256) void prep2_kernel(
    const float* __restrict__ emb, const double* __restrict__ wa_dst,
    const double* __restrict__ wa_src, double* __restrict__ s_dst,
    double* __restrict__ s_src, float* __restrict__ s_dst_f,
    float* __restrict__ s_src_f, const int* __restrict__ eidx,
    const float* __restrict__ ew, int* __restrict__ cnt,
    int4* __restrict__ etab, int N, int E, int cap, int sblocks) {
    const int b = blockIdx.x;
    const int tid = threadIdx.x;

    if (b < sblocks) {
        __shared__ double wa_l[8][258];   // +2 pad: conflict-free
        __shared__ float emb_l[SROWS][258];
        const int i0 = b * SROWS;
#pragma unroll
        for (int c = 0; c < 8; ++c)
            wa_l[c][tid] = ((c & 1) ? wa_src : wa_dst)[(c >> 1) * H_DIM + tid];
#pragma unroll
        for (int r = 0; r < SROWS; ++r)
            emb_l[r][tid] = emb[(size_t)(i0 + r) * H_DIM + tid];
        __syncthreads();

        const int j = tid >> 1;        // job 0..127: row r=j>>3, combo c=j&7
        const int half = tid & 1;      // low/high 128-element half
        const int r = j >> 3;
        const int c = j & 7;
        const int base = half * 128;
        double acc = 0.0;
#pragma unroll 8
        for (int k = 0; k < 128; ++k)
            acc += (double)emb_l[r][base + k] * wa_l[c][base + k];
        const double other = __shfl_xor(acc, 1, 64);
        const double lo = half ? other : acc;
        const double hi = half ? acc : other;
        const double s = lo + hi;      // fixed order: low half + high half
        if (half == 0) {
            const int i = i0 + r;
            const int h = c >> 1;
            if (c & 1) {
                s_src[i * HEADS + h] = s;
                s_src_f[i * HEADS + h] = (float)s;
            } else {
                s_dst[i * HEADS + h] = s;
                s_dst_f[i * HEADS + h] = (float)s;
            }
        }
    } else {
        // ---- edge-table build (slot order nondeterministic; dedup is by max
        // edge id, which is order-independent) ----
        const int e = (b - sblocks) * 256 + tid;
        if (e < E) {
            const int r = eidx[e];
            const int cc = eidx[E + e];
            const int s = atomicAdd(&cnt[r], 1);
            if (s < cap) {
                int4 rec;
                rec.x = cc;
                rec.y = e;
                rec.z = __float_as_int(ew[e]);
                rec.w = 0;
                etab[r * cap + s] = rec;
            }
        }
    }
}

#define FOR16(OP) OP(0) OP(1) OP(2) OP(3) OP(4) OP(5) OP(6) OP(7) \
                  OP(8) OP(9) OP(10) OP(11) OP(12) OP(13) OP(14) OP(15)

// One block per row. Wave-local ownership: thread (wave w, lane l) owns
// columns j = (w<<10)|(k<<6)|l; mask bit-transpose via 16 intra-wave
// shuffles, done BEFORE the barrier so the mask-load wait overlaps the
// edge-load drain. Winner adds via 8 KB ushort index table + fp32/fp64 add
// arrays. Tail (4a/4b/5) runs on wave 0 alone — no barriers after FILT,
// waves 1-3 retire early. fp32 selection (truncated+relaxed ballot
// threshold -> provable superset); exact fp64 re-rank by (value, index) ->
// output identical to all-fp64.
__global__ __launch_bounds__(256, 8) void main_kernel(
    const double* __restrict__ s_dst, const double* __restrict__ s_src,
    const float* __restrict__ s_dst_f, const float* __restrict__ s_src_f,
    const int* __restrict__ sector_mask, const unsigned short* __restrict__ abits16,
    const int* __restrict__ active, const float* __restrict__ lam_p,
    const int* __restrict__ cnt, const int4* __restrict__ etab,
    float* __restrict__ out, int N, int cap) {
    const int i = blockIdx.x;
    const int tid = threadIdx.x;
    const int lane = tid & 63;
    const int wid = tid >> 6;

    __shared__ int ec[EDGE_CAP_MAX];
    __shared__ int ee[EDGE_CAP_MAX];
    __shared__ float ewl[EDGE_CAP_MAX];
    __shared__ double wadd[EDGE_CAP_MAX];      // fp64 winner add by slot
    __shared__ unsigned short tab16[4096];     // winner slot+1 per column (8 KB)
    __shared__ float waddf[EDGE_CAP_MAX + 2];  // fp32 adds; [0] = 0.0 sentinel
    __shared__ unsigned int wth[4];
    __shared__ double cand_v[CAND_CAP];
    __shared__ int cand_i[CAND_CAP];
    __shared__ int cand_cnt, wcnt;
    __shared__ double sorted_v[TOPK];
    __shared__ int sorted_i[TOPK];
    __shared__ double exps[TOPK];

    // Issue the coalesced mask-row loads FIRST (64 B/thread); everything up
    // to the pb pack runs while they are in flight.
    const int* mrow = sector_mask + (size_t)i * N;
    const int4 m0 = *(const int4*)(mrow + 16 * tid);
    const int4 m1 = *(const int4*)(mrow + 16 * tid + 4);
    const int4 m2 = *(const int4*)(mrow + 16 * tid + 8);
    const int4 m3 = *(const int4*)(mrow + 16 * tid + 12);
    const unsigned int act_us = (unsigned int)abits16[tid];

    if (tid == 0) { cand_cnt = 0; wcnt = 0; waddf[0] = 0.0f; }

    // Zero tab16 as 2048 ints at dword stride-256: conflict-free.
    {
        int* t4 = (int*)tab16;
#pragma unroll
        for (int z = 0; z < 8; ++z) t4[tid + (z << 8)] = 0;
    }

    // Stage this row's edge slice (one int4 per edge, unpacked to scalar LDS
    // arrays) — its L2 latency overlaps the in-flight mask loads.
    int deg = cnt[i];
    if (deg > cap) deg = cap;
    for (int p = tid; p < deg; p += 256) {
        const int4 rec = etab[i * cap + p];
        ec[p] = rec.x;
        ee[p] = rec.y;
        ewl[p] = __int_as_float(rec.z);
    }

    // Consume mask loads pre-barrier (pack + intra-wave transpose, no LDS):
    unsigned int pb = 0;
#define PB(C, VAL) if ((VAL) != 0) pb |= (1u << (C));
    PB(0, m0.x)  PB(1, m0.y)  PB(2, m0.z)  PB(3, m0.w)
    PB(4, m1.x)  PB(5, m1.y)  PB(6, m1.z)  PB(7, m1.w)
    PB(8, m2.x)  PB(9, m2.y)  PB(10, m2.z) PB(11, m2.w)
    PB(12, m3.x) PB(13, m3.y) PB(14, m3.z) PB(15, m3.w)
#undef PB
    pb &= act_us;

    // Intra-wave bit-transpose: col j=(wid<<10)|(k<<6)|lane was loaded by
    // lane 4k+(lane>>4) of the SAME wave, bit (lane&15) of its pb.
    const int lhi = lane >> 4;
    const int llo = lane & 15;
    unsigned int pm = 0;
#pragma unroll
    for (int k = 0; k < 16; ++k) {
        const unsigned int opb = (unsigned int)__shfl((int)pb, 4 * k + lhi, 64);
        pm |= ((opb >> llo) & 1u) << k;
    }
    if (active[i] == 0) pm = 0;

    __syncthreads();  // edges + zeroed table + counters visible (edge loads
                      // finished during the mask wait — single drain)

    // fp32 sd for selection; fp64 sd for exact re-rank
    const float sdf0 = s_dst_f[i * 4 + 0];
    const float sdf1 = s_dst_f[i * 4 + 1];
    const float sdf2 = s_dst_f[i * 4 + 2];
    const float sdf3 = s_dst_f[i * 4 + 3];
    const double sd0 = s_dst[i * 4 + 0];
    const double sd1 = s_dst[i * 4 + 1];
    const double sd2 = s_dst[i * 4 + 2];
    const double sd3 = s_dst[i * 4 + 3];
    const double lam = (double)lam_p[0];
    const double4* __restrict__ s_src4 = (const double4*)s_src;
    const float4* __restrict__ s_srcf4 = (const float4*)s_src_f;
    const int jbase = (wid << 10) | lane;  // owned column for k: jbase + (k<<6)

    // Phase 1 (fp32): scores into 16 named registers (coalesced per-wave)
    float f0, f1, f2, f3, f4, f5, f6, f7, f8, f9, f10, f11, f12, f13, f14, f15;
#define INIT_SLOT(K) { \
    const bool m = (pm >> K) & 1u; \
    const float4 sv = s_srcf4[jbase + (K << 6)]; \
    float x0 = sdf0 + sv.x, x1 = sdf1 + sv.y, x2 = sdf2 + sv.z, x3 = sdf3 + sv.w; \
    x0 = (x0 < 0.0f) ? NSLOPEF * x0 : x0; \
    x1 = (x1 < 0.0f) ? NSLOPEF * x1 : x1; \
    x2 = (x2 < 0.0f) ? NSLOPEF * x2 : x2; \
    x3 = (x3 < 0.0f) ? NSLOPEF * x3 : x3; \
    f##K = m ? (0.25f * (x0 + x1 + x2 + x3)) : -INFINITY; }
    FOR16(INIT_SLOT)
#undef INIT_SLOT

    // Phase 2a: parallel dedup (last-write-wins by edge id), thread-per-edge.
    // Winners: slot index into tab16 (unique columns -> conflict-free) +
    // fp64/fp32 adds by slot.
    if (tid < deg) {
        const int c = ec[tid];
        const int eid = ee[tid];
        bool win = true;
        for (int q = 0; q < deg; ++q)
            if (ec[q] == c && ee[q] > eid) win = false;
        if (win) {
            const double a = lam * (double)ewl[tid];
            int p = atomicAdd(&wcnt, 1);
            wadd[p] = a;
            waddf[p + 1] = (float)a;
            tab16[c] = (unsigned short)(p + 1);
        }
    }
    __syncthreads();

    // Phase 2b (fp32): branchless gather (x+0.0f == x; -0.0f+0.0f -> +0.0f
    // shifts a key 1 step — absorbed by the relax; fp64 re-rank recomputes).
#define ADDG(K) f##K += waddf[tab16[jbase + (K << 6)]];
    FOR16(ADDG)
#undef ADDG

    // Phase 3a: fp32 monotone keys + per-thread local max
    unsigned int k0, k1, k2, k3, k4, k5, k6, k7, k8, k9, k10, k11, k12, k13, k14, k15;
#define KEY_SLOT(K) { const unsigned u = __float_as_uint(f##K); \
    k##K = u ^ ((unsigned)((int)u >> 31) | 0x80000000u); }
    FOR16(KEY_SLOT)
#undef KEY_SLOT
    unsigned int lmax = k0;
#define LMAX(K) if (k##K > lmax) lmax = k##K;
    FOR16(LMAX)
#undef LMAX

    // Phase 3b: per-wave 15th-largest lane-max via ballot binary search,
    // truncated to the top 24 bits (threshold only gets lower -> still a
    // valid lower bound on the row's true 15th value).
    unsigned int th = 0;
    for (int b = 31; b >= 8; --b) {
        const unsigned int trial = th | (1u << b);
        unsigned long long m = __ballot(lmax >= trial);
        if (__popcll(m) >= TOPK) th = trial;
    }
    if (lane == 0) wth[wid] = th;
    __syncthreads();
    th = wth[0];
    if (wth[1] > th) th = wth[1];
    if (wth[2] > th) th = wth[2];
    if (wth[3] > th) th = wth[3];
    // Relax by 256 ulp: covers fp32-vs-fp64 ordering divergence near the cut.
    th = (th > 256u) ? (th - 256u) : 0u;

    // Phase 3c: candidate filter (store actual column index)
#define FILT(K) if (k##K >= th) { int p = atomicAdd(&cand_cnt, 1); \
    if (p < CAND_CAP) cand_i[p] = jbase + (K << 6); }
    FOR16(FILT)
#undef FILT
    __syncthreads();  // last block-wide barrier — waves 1..3 retire after this

    // Tail: single wave (intra-wave LDS ordering needs no barriers).
    if (wid == 0) {
        int C = cand_cnt;
        if (C > CAND_CAP) C = CAND_CAP;

        // Phase 4a: exact fp64 re-score of each candidate (same expression
        // order as the all-fp64 kernel; winner lookup via tab16)
        for (int base = 0; base < C; base += 64) {
            const int t = base + lane;
            if (t < C) {
                const int j = cand_i[t];
                const double4 sv = s_src4[j];
                double x0 = sd0 + sv.x, x1 = sd1 + sv.y;
                double x2 = sd2 + sv.z, x3 = sd3 + sv.w;
                x0 = (x0 < 0.0) ? NSLOPE * x0 : x0;
                x1 = (x1 < 0.0) ? NSLOPE * x1 : x1;
                x2 = (x2 < 0.0) ? NSLOPE * x2 : x2;
                x3 = (x3 < 0.0) ? NSLOPE * x3 : x3;
                double v = 0.25 * (x0 + x1 + x2 + x3);
                const int slot = tab16[j];
                if (slot) v += wadd[slot - 1];
                cand_v[t] = v;
            }
        }

        // Phase 4b: exact fp64 rank-by-counting (unique ranks via index tie-break)
        for (int base = 0; base < C; base += 64) {
            const int t = base + lane;
            if (t < C) {
                const double mv = cand_v[t];
                const int mi = cand_i[t];
                int rank = 0;
                for (int q = 0; q < C; ++q) {
                    const double qv = cand_v[q];
                    const int qi = cand_i[q];
                    rank += ((qv > mv) || (qv == mv && qi < mi)) ? 1 : 0;
                }
                if (rank < TOPK) { sorted_v[rank] = mv; sorted_i[rank] = mi; }
            }
        }

        // Phase 5: softmax + store (fp64)
        if (lane < TOPK) exps[lane] = exp(sorted_v[lane] - sorted_v[0]);
        if (lane < TOPK) {
            double s = 0.0;
            for (int t = 0; t < TOPK; ++t) s += exps[t];
            const int NK = N * TOPK;
            const int base = i * TOPK + lane;
            out[base] = (float)sorted_i[lane];     // edge_index row 0: topk col idx
            out[NK + base] = (float)i;             // edge_index row 1: source row
            out[2 * NK + base] = (float)(exps[lane] / s);  // edge_weight (softmax)
        }
    }
}

extern "C" void kernel_launch(void* const* d_in, const int* in_sizes, int n_in,
                              void* d_out, int out_size, void* d_ws, size_t ws_size,
                              hipStream_t stream) {
    const float* emb    = (const float*)d_in[0];
    const float* W      = (const float*)d_in[1];
    const float* att    = (const float*)d_in[2];
    const float* lam    = (const float*)d_in[3];
    const int*   sector = (const int*)d_in[4];
    const int*   active = (const int*)d_in[5];
    const int*   eidx   = (const int*)d_in[6];
    const float* ew     = (const float*)d_in[7];
    float* out = (float*)d_out;

    const int N = in_sizes[5];      // 4096
    const int E = in_sizes[6] / 2;  // 131072

    // workspace layout
    double* wa_dst = (double*)d_ws;                       // 1024 dbl
    double* wa_src = wa_dst + HEADS * H_DIM;              // 1024 dbl
    double* s_dst  = wa_src + HEADS * H_DIM;              // N*4 dbl
    double* s_src  = s_dst + (size_t)N * HEADS;           // N*4 dbl
    float* s_dst_f = (float*)(s_src + (size_t)N * HEADS); // N*4 f32
    float* s_src_f = s_dst_f + (size_t)N * HEADS;         // N*4 f32
    int* cnt       = (int*)(s_src_f + (size_t)N * HEADS); // N int
    unsigned int* abits = (unsigned int*)(cnt + N);       // N/32 uint
    // 16B-align the edge table
    uintptr_t ep = (uintptr_t)(abits + N / 32);
    ep = (ep + 15) & ~(uintptr_t)15;
    int4* etab = (int4*)ep;

    size_t used = (ep - (uintptr_t)d_ws) + 64;
    size_t rem = (ws_size > used) ? (ws_size - used) : 0;
    int cap = (int)(rem / ((size_t)N * 16));
    if (cap > EDGE_CAP_MAX) cap = EDGE_CAP_MAX;
    if (cap < 16) cap = 16;

    const int nb = (E + 255) / 256;   // edge-build blocks (512)
    const int sblocks = N / SROWS;    // s-compute blocks (256)

    prep1_kernel<<<16, 256, 0, stream>>>(W, att, wa_dst, wa_src, cnt, abits, active);
    prep2_kernel<<<sblocks + nb, 256, 0, stream>>>(emb, wa_dst, wa_src, s_dst, s_src,
                                                   s_dst_f, s_src_f, eidx, ew, cnt,
                                                   etab, N, E, cap, sblocks);
    main_kernel<<<N, 256, 0, stream>>>(s_dst, s_src, s_dst_f, s_src_f, sector,
                                       (const unsigned short*)abits, active, lam, cnt,
                                       etab, out, N, cap);
}